// Round 1
// baseline (152.767 us; speedup 1.0000x reference)
//
#include <hip/hip_runtime.h>

// PillarFeatureNet fused: moments -> BN stats -> per-pillar GEMM(9x64)+max.
// features [K,P,4] f32, num_voxels [K] i32, coors [K,4] i32,
// W [9,64] f32, gamma/beta [64] f32 -> out [K,64] f32.

#define NM 54  // 9 first moments + 45 upper-tri second moments

__device__ __forceinline__ float wave_reduce_sum(float v) {
#pragma unroll
  for (int off = 1; off < 64; off <<= 1) v += __shfl_xor(v, off, 64);
  return v;
}

// Pass 1: per-wave partial moment sums of the masked 9-dim augmented features.
__global__ void __launch_bounds__(256) pfn_moments(
    const float4* __restrict__ feat, const int* __restrict__ nvox,
    const int* __restrict__ coors, int K, int P,
    float* __restrict__ partials, int nwaves) {
  const int lane = threadIdx.x & 63;
  const int gw = (blockIdx.x * blockDim.x + threadIdx.x) >> 6;

  float acc[NM];
#pragma unroll
  for (int i = 0; i < NM; ++i) acc[i] = 0.f;

  for (int k = gw; k < K; k += nwaves) {
    // per-pillar mean over ALL P points (reference sums unmasked, divides by nv)
    float sx = 0.f, sy = 0.f, sz = 0.f;
    for (int p = lane; p < P; p += 64) {
      float4 f = feat[k * P + p];
      sx += f.x; sy += f.y; sz += f.z;
    }
    sx = wave_reduce_sum(sx);
    sy = wave_reduce_sum(sy);
    sz = wave_reduce_sum(sz);
    const int nv = nvox[k];
    const float nvf = (float)nv;
    const float mx = sx / nvf, my = sy / nvf, mz = sz / nvf;
    const float cx = (float)coors[k * 4 + 3] * 0.2f + 0.1f;
    const float cy = (float)coors[k * 4 + 2] * 0.2f - 39.9f;

    // valid points only (masked points contribute exact zeros)
    for (int p = lane; p < nv; p += 64) {
      float4 f = feat[k * P + p];
      float ft[9] = {f.x, f.y, f.z, f.w, f.x - mx, f.y - my, f.z - mz,
                     f.x - cx, f.y - cy};
#pragma unroll
      for (int c = 0; c < 9; ++c) acc[c] += ft[c];
      int idx = 9;
#pragma unroll
      for (int c = 0; c < 9; ++c)
#pragma unroll
        for (int c2 = c; c2 < 9; ++c2) {
          acc[idx] += ft[c] * ft[c2];
          ++idx;
        }
    }
  }

#pragma unroll
  for (int i = 0; i < NM; ++i) acc[i] = wave_reduce_sum(acc[i]);
  if (lane == 0) {
#pragma unroll
    for (int i = 0; i < NM; ++i) partials[i * nwaves + gw] = acc[i];
  }
}

// Pass 2: reduce partials, produce per-channel scale/shift. 1 block x 64 thr.
__global__ void pfn_finalize(const float* __restrict__ partials, int nwaves,
                             const float* __restrict__ W,
                             const float* __restrict__ gamma,
                             const float* __restrict__ beta, float invN,
                             float* __restrict__ ss) {
  __shared__ float sm[NM];
  const int t = threadIdx.x;  // 64 threads; t = output channel
  if (t < NM) {
    float s = 0.f;
    const float* p = partials + t * nwaves;
    for (int w = 0; w < nwaves; ++w) s += p[w];
    sm[t] = s;
  }
  __syncthreads();

  float wc[9];
#pragma unroll
  for (int c = 0; c < 9; ++c) wc[c] = W[c * 64 + t];

  float mu = 0.f;
#pragma unroll
  for (int c = 0; c < 9; ++c) mu += sm[c] * invN * wc[c];

  float ex2 = 0.f;
  int idx = 9;
#pragma unroll
  for (int c = 0; c < 9; ++c)
#pragma unroll
    for (int c2 = c; c2 < 9; ++c2) {
      float v = sm[idx] * invN * wc[c] * wc[c2];
      ex2 += (c == c2) ? v : 2.f * v;
      ++idx;
    }
  float var = ex2 - mu * mu;
  float scale = gamma[t] * rsqrtf(var + 1e-3f);
  float shift = beta[t] - mu * scale;
  ss[t] = scale;
  ss[64 + t] = shift;
}

// Pass 3: wave per pillar, lane = channel. Raw max/min over valid points,
// masked points contribute raw 0, then BN affine + relu on the extremum.
__global__ void __launch_bounds__(256) pfn_out(
    const float4* __restrict__ feat, const int* __restrict__ nvox,
    const int* __restrict__ coors, const float* __restrict__ W,
    const float* __restrict__ ss, int K, int P, float* __restrict__ out) {
  const int lane = threadIdx.x & 63;
  const int k = blockIdx.x * 4 + (threadIdx.x >> 6);
  if (k >= K) return;

  const float w0 = W[0 * 64 + lane], w1 = W[1 * 64 + lane];
  const float w2 = W[2 * 64 + lane], w3 = W[3 * 64 + lane];
  const float w4 = W[4 * 64 + lane], w5 = W[5 * 64 + lane];
  const float w6 = W[6 * 64 + lane], w7 = W[7 * 64 + lane];
  const float w8 = W[8 * 64 + lane];
  const float scale = ss[lane], shift = ss[64 + lane];

  // per-pillar xyz mean
  float sx = 0.f, sy = 0.f, sz = 0.f;
  for (int p = lane; p < P; p += 64) {
    float4 f = feat[k * P + p];
    sx += f.x; sy += f.y; sz += f.z;
  }
  sx = wave_reduce_sum(sx);
  sy = wave_reduce_sum(sy);
  sz = wave_reduce_sum(sz);
  const int nv = nvox[k];
  const float nvf = (float)nv;
  const float mx = sx / nvf, my = sy / nvf, mz = sz / nvf;
  const float cx = (float)coors[k * 4 + 3] * 0.2f + 0.1f;
  const float cy = (float)coors[k * 4 + 2] * 0.2f - 39.9f;

  // fold W columns: x = f.x*wxs + f.y*wys + f.z*wzs + f.w*w3 + bias
  const float wxs = w0 + w4 + w7;
  const float wys = w1 + w5 + w8;
  const float wzs = w2 + w6;
  const float bias = -(mx * w4 + my * w5 + mz * w6 + cx * w7 + cy * w8);

  float vmax = -1e30f, vmin = 1e30f;
  for (int p = 0; p < nv; ++p) {
    float4 f = feat[k * P + p];  // broadcast load (same addr across lanes)
    float x = fmaf(f.x, wxs, fmaf(f.y, wys, fmaf(f.z, wzs, fmaf(f.w, w3, bias))));
    vmax = fmaxf(vmax, x);
    vmin = fminf(vmin, x);
  }
  if (nv < P) {  // masked points: raw x == 0
    vmax = fmaxf(vmax, 0.f);
    vmin = fminf(vmin, 0.f);
  }
  const float sel = (scale >= 0.f) ? vmax : vmin;
  out[k * 64 + lane] = fmaxf(fmaf(scale, sel, shift), 0.f);
}

extern "C" void kernel_launch(void* const* d_in, const int* in_sizes, int n_in,
                              void* d_out, int out_size, void* d_ws,
                              size_t ws_size, hipStream_t stream) {
  const float4* feat = (const float4*)d_in[0];
  const int* nvox = (const int*)d_in[1];
  const int* coors = (const int*)d_in[2];
  const float* W = (const float*)d_in[3];
  const float* gamma = (const float*)d_in[4];
  const float* beta = (const float*)d_in[5];
  float* out = (float*)d_out;

  const int K = in_sizes[1];
  const int P = in_sizes[0] / (K * 4);

  float* ss = (float*)d_ws;    // [128]: scale, shift
  float* partials = ss + 128;  // [NM * nwaves]

  // keep partials within ws_size (defensive)
  int blocks1 = 128;
  const size_t avail = (ws_size / 4 > 128) ? (ws_size / 4 - 128) : 0;
  while (blocks1 > 1 && (size_t)(NM * blocks1 * 4) > avail) blocks1 >>= 1;
  const int nwaves = blocks1 * 4;  // 256 threads = 4 waves per block

  pfn_moments<<<blocks1, 256, 0, stream>>>(feat, nvox, coors, K, P, partials,
                                           nwaves);
  pfn_finalize<<<1, 64, 0, stream>>>(partials, nwaves, W, gamma, beta,
                                     1.0f / (float)((long long)K * P), ss);
  pfn_out<<<(K + 3) / 4, 256, 0, stream>>>(feat, nvox, coors, W, ss, K, P, out);
}

// Round 2
// 81.966 us; speedup vs baseline: 1.8638x; 1.8638x over previous
//
#include <hip/hip_runtime.h>

// PillarFeatureNet fused: moments(atomic) -> BN stats -> per-pillar GEMM(9x64)+max.
// features [K,P,4] f32, num_voxels [K] i32, coors [K,4] i32,
// W [9,64] f32, gamma/beta [64] f32 -> out [K,64] f32.
//
// ws layout: ws[0..53] = global moment sums (atomicAdd, memset to 0 each call)
//            ws[64..191] = per-channel scale/shift

#define NM 54  // 9 first moments + 45 upper-tri second moments

__device__ __forceinline__ float wave_reduce_sum(float v) {
#pragma unroll
  for (int off = 1; off < 64; off <<= 1) v += __shfl_xor(v, off, 64);
  return v;
}

// Pass A: per-wave moment accumulation over grid-strided pillars,
// block-level LDS reduce, one atomicAdd per moment per block.
__global__ void __launch_bounds__(256) pfn_stats(
    const float4* __restrict__ feat, const int* __restrict__ nvox,
    const int* __restrict__ coors, int K, int P, int nwaves,
    float* __restrict__ msum) {
  const int lane = threadIdx.x & 63;
  const int wid = threadIdx.x >> 6;
  const int gw = (blockIdx.x * blockDim.x + threadIdx.x) >> 6;

  float acc[NM];
#pragma unroll
  for (int i = 0; i < NM; ++i) acc[i] = 0.f;

  for (int k = gw; k < K; k += nwaves) {
    // per-pillar xyz mean: sum over ALL P points, divide by nv (ref semantics)
    float sx = 0.f, sy = 0.f, sz = 0.f;
    for (int p = lane; p < P; p += 64) {
      float4 f = feat[k * P + p];
      sx += f.x; sy += f.y; sz += f.z;
    }
    sx = wave_reduce_sum(sx);
    sy = wave_reduce_sum(sy);
    sz = wave_reduce_sum(sz);
    const int nv = nvox[k];
    const float inv = 1.f / (float)nv;
    const float mx = sx * inv, my = sy * inv, mz = sz * inv;
    const float cx = (float)coors[k * 4 + 3] * 0.2f + 0.1f;
    const float cy = (float)coors[k * 4 + 2] * 0.2f - 39.9f;

    // moments over valid points only (masked points are exact zeros)
    for (int p = lane; p < nv; p += 64) {
      float4 f = feat[k * P + p];
      float ft[9] = {f.x, f.y, f.z, f.w, f.x - mx, f.y - my, f.z - mz,
                     f.x - cx, f.y - cy};
#pragma unroll
      for (int c = 0; c < 9; ++c) acc[c] += ft[c];
      int idx = 9;
#pragma unroll
      for (int c = 0; c < 9; ++c)
#pragma unroll
        for (int c2 = c; c2 < 9; ++c2) {
          acc[idx] += ft[c] * ft[c2];
          ++idx;
        }
    }
  }

#pragma unroll
  for (int i = 0; i < NM; ++i) acc[i] = wave_reduce_sum(acc[i]);

  __shared__ float sm[4][NM];
  if (lane == 0) {
#pragma unroll
    for (int i = 0; i < NM; ++i) sm[wid][i] = acc[i];
  }
  __syncthreads();
  const int t = threadIdx.x;
  if (t < NM) {
    atomicAdd(&msum[t], sm[0][t] + sm[1][t] + sm[2][t] + sm[3][t]);
  }
}

// Pass B: per-channel scale/shift from the 54 moment sums. 1 block x 64 thr.
__global__ void pfn_finalize(const float* __restrict__ msum,
                             const float* __restrict__ W,
                             const float* __restrict__ gamma,
                             const float* __restrict__ beta, float invN,
                             float* __restrict__ ss) {
  const int t = threadIdx.x;  // output channel

  float wc[9];
#pragma unroll
  for (int c = 0; c < 9; ++c) wc[c] = W[c * 64 + t];

  float mu = 0.f;
#pragma unroll
  for (int c = 0; c < 9; ++c) mu += msum[c] * invN * wc[c];

  float ex2 = 0.f;
  int idx = 9;
#pragma unroll
  for (int c = 0; c < 9; ++c)
#pragma unroll
    for (int c2 = c; c2 < 9; ++c2) {
      float v = msum[idx] * invN * wc[c] * wc[c2];
      ex2 += (c == c2) ? v : 2.f * v;
      ++idx;
    }
  float var = ex2 - mu * mu;
  float scale = gamma[t] * rsqrtf(var + 1e-3f);
  float shift = beta[t] - mu * scale;
  ss[t] = scale;
  ss[64 + t] = shift;
}

// Pass C: wave per pillar, lane = channel. Extrema of the bias-free dot
// product over valid points; per-pillar bias applied post-hoc (constant
// over points); masked points contribute raw 0; BN affine + relu at end.
__global__ void __launch_bounds__(256) pfn_out(
    const float4* __restrict__ feat, const int* __restrict__ nvox,
    const int* __restrict__ coors, const float* __restrict__ W,
    const float* __restrict__ ss, int K, int P, float* __restrict__ out) {
  const int lane = threadIdx.x & 63;
  const int k = blockIdx.x * 4 + (threadIdx.x >> 6);
  if (k >= K) return;

  const float w0 = W[0 * 64 + lane], w1 = W[1 * 64 + lane];
  const float w2 = W[2 * 64 + lane], w3 = W[3 * 64 + lane];
  const float w4 = W[4 * 64 + lane], w5 = W[5 * 64 + lane];
  const float w6 = W[6 * 64 + lane], w7 = W[7 * 64 + lane];
  const float w8 = W[8 * 64 + lane];
  const float scale = ss[lane], shift = ss[64 + lane];

  // per-pillar xyz mean (strided, coalesced)
  float sx = 0.f, sy = 0.f, sz = 0.f;
  for (int p = lane; p < P; p += 64) {
    float4 f = feat[k * P + p];
    sx += f.x; sy += f.y; sz += f.z;
  }
  sx = wave_reduce_sum(sx);
  sy = wave_reduce_sum(sy);
  sz = wave_reduce_sum(sz);
  const int nv = nvox[k];
  const float inv = 1.f / (float)nv;
  const float mx = sx * inv, my = sy * inv, mz = sz * inv;
  const float cx = (float)coors[k * 4 + 3] * 0.2f + 0.1f;
  const float cy = (float)coors[k * 4 + 2] * 0.2f - 39.9f;

  // folded weights; bias is constant over points -> applied after extrema
  const float wxs = w0 + w4 + w7;
  const float wys = w1 + w5 + w8;
  const float wzs = w2 + w6;
  const float bias = -(mx * w4 + my * w5 + mz * w6 + cx * w7 + cy * w8);

  float bmax = -3e38f, bmin = 3e38f;
#pragma unroll 4
  for (int p = 0; p < nv; ++p) {
    float4 f = feat[k * P + p];  // broadcast load, L1/L2-hot from mean pass
    float b = fmaf(f.x, wxs, fmaf(f.y, wys, fmaf(f.z, wzs, f.w * w3)));
    bmax = fmaxf(bmax, b);
    bmin = fminf(bmin, b);
  }
  float vmax = bmax + bias, vmin = bmin + bias;
  if (nv < P) {  // masked points: raw x == 0
    vmax = fmaxf(vmax, 0.f);
    vmin = fminf(vmin, 0.f);
  }
  const float sel = (scale >= 0.f) ? vmax : vmin;
  out[k * 64 + lane] = fmaxf(fmaf(scale, sel, shift), 0.f);
}

extern "C" void kernel_launch(void* const* d_in, const int* in_sizes, int n_in,
                              void* d_out, int out_size, void* d_ws,
                              size_t ws_size, hipStream_t stream) {
  const float4* feat = (const float4*)d_in[0];
  const int* nvox = (const int*)d_in[1];
  const int* coors = (const int*)d_in[2];
  const float* W = (const float*)d_in[3];
  const float* gamma = (const float*)d_in[4];
  const float* beta = (const float*)d_in[5];
  float* out = (float*)d_out;

  const int K = in_sizes[1];
  const int P = in_sizes[0] / (K * 4);

  float* msum = (float*)d_ws;  // [54]
  float* ss = msum + 64;       // [128]: scale, shift

  hipMemsetAsync(d_ws, 0, NM * sizeof(float), stream);

  const int blocksA = 512;  // 2048 waves, ~10 pillars/wave
  pfn_stats<<<blocksA, 256, 0, stream>>>(feat, nvox, coors, K, P, blocksA * 4,
                                         msum);
  pfn_finalize<<<1, 64, 0, stream>>>(msum, W, gamma, beta,
                                     1.0f / (float)((long long)K * P), ss);
  pfn_out<<<(K + 3) / 4, 256, 0, stream>>>(feat, nvox, coors, W, ss, K, P, out);
}